// Round 1
// baseline (43738.675 us; speedup 1.0000x reference)
//
#include <hip/hip_runtime.h>
#include <hip/hip_bf16.h>

// LSTM classifier: emb gather -> input GEMM (fp16 MFMA) -> persistent
// recurrence kernel (flag-synced, 2 batch-groups x 128 WGs) -> logits.
//
// Workspace layout (bytes):
//   emb16   @ 0          : 50257*1024*2 = 102,926,336
//   wih16   @ 102926336  : 4096*1024*2  =   8,388,608
//   wr16    @ 111314944  : 4096*1024*2  =   8,388,608   (W_hh reordered, fp16)
//   bias    @ 119703552  : 4096*4       =      16,384   (b_ih + b_hh, f32)
//   xg      @ 119719936  : 65536*4096*2 = 536,870,912   (x_gates fp16, [t][b][4096])
//   h_all   @ 656590848  : 2049*32*1024*2 = 134,283,264 (h per step, fp16)
//   cnt     @ 790874112  : 2*2049*4     =      16,392   (per-group step counters)
//   total: 790,890,504

typedef _Float16 f16;
typedef _Float16 f16x8 __attribute__((ext_vector_type(8)));
typedef _Float16 f16x4 __attribute__((ext_vector_type(4)));
typedef float    f32x4 __attribute__((ext_vector_type(4)));

#define B_    32
#define T_    2048
#define W_    1024
#define H_    1024
#define G4_   4096

__device__ __forceinline__ void gl_lds16(const void* g, void* l) {
  __builtin_amdgcn_global_load_lds(
      (const __attribute__((address_space(1))) void*)g,
      (__attribute__((address_space(3))) void*)l, 16, 0, 0);
}

// ---------------- conversions ----------------

__global__ void k_cvt_f16(const float* __restrict__ in, f16* __restrict__ out, long n4) {
  long i = (long)blockIdx.x * blockDim.x + threadIdx.x;
  if (i >= n4) return;
  float4 v = ((const float4*)in)[i];
  f16x4 o; o[0] = (f16)v.x; o[1] = (f16)v.y; o[2] = (f16)v.z; o[3] = (f16)v.w;
  *(f16x4*)(out + i * 4) = o;
}

// W_hh row (q*1024 + j) -> wr16 row ((j>>3)*32 + (j&7)*4 + q); fp16.
__global__ void k_whh_reorder(const float* __restrict__ whh, f16* __restrict__ wr) {
  unsigned i = blockIdx.x * blockDim.x + threadIdx.x;   // one thread per 8 elems
  unsigned e0 = i * 8;
  unsigned R = e0 >> 10, k = e0 & 1023;
  unsigned q = R >> 10, j = R & 1023;
  unsigned outR = ((j >> 3) << 5) + ((j & 7) << 2) + q;
  float4 v0 = ((const float4*)whh)[e0 / 4];
  float4 v1 = ((const float4*)whh)[e0 / 4 + 1];
  f16x8 o;
  o[0] = (f16)v0.x; o[1] = (f16)v0.y; o[2] = (f16)v0.z; o[3] = (f16)v0.w;
  o[4] = (f16)v1.x; o[5] = (f16)v1.y; o[6] = (f16)v1.z; o[7] = (f16)v1.w;
  *(f16x8*)&wr[((size_t)outR << 10) + k] = o;
}

__global__ void k_bias(const float* __restrict__ bi, const float* __restrict__ bh,
                       float* __restrict__ bo) {
  unsigned i = blockIdx.x * blockDim.x + threadIdx.x;
  if (i < G4_) bo[i] = bi[i] + bh[i];
}

// ---------------- input GEMM: xg[m][n] = emb[seq] @ W_ih^T + bias ----------------
// m = t*32 + b (so xg layout is [t][b][4096]); 128x128 tile, BK=64, 4 waves.

__global__ __launch_bounds__(256) void k_gemm_xg(
    const int* __restrict__ seq, const f16* __restrict__ emb16,
    const f16* __restrict__ wih16, const float* __restrict__ bias,
    f16* __restrict__ xg) {
  __shared__ f16 As[128 * 64];
  __shared__ f16 Bs[128 * 64];
  const unsigned tid = threadIdx.x;
  const unsigned w = tid >> 6, lane = tid & 63;
  const unsigned bid = blockIdx.x;
  const unsigned tn = bid & 31, tm = bid >> 5;
  const unsigned wm = (w >> 1) * 64, wn = (w & 1) * 64;

  f32x4 zero = {0.f, 0.f, 0.f, 0.f};
  f32x4 acc[4][4];
#pragma unroll
  for (int i = 0; i < 4; ++i)
#pragma unroll
    for (int j = 0; j < 4; ++j) acc[i][j] = zero;

  for (unsigned kk = 0; kk < 16; ++kk) {
    const unsigned k0 = kk * 64;
    // stage A (gathered emb rows), pre-swizzled source chunks
#pragma unroll
    for (unsigned c = 0; c < 4; ++c) {
      unsigned idx = c * 256 + tid;
      unsigned row = idx >> 3, ch = idx & 7;
      unsigned chs = ch ^ (row & 7);
      unsigned m = tm * 128 + row;
      unsigned t = m >> 5, b = m & 31;
      int e = seq[b * 2048 + t];
      const f16* src = emb16 + ((size_t)e << 10) + k0 + chs * 8;
      gl_lds16(src, (char*)As + c * 4096 + w * 1024);
    }
    // stage B (W_ih rows)
#pragma unroll
    for (unsigned c = 0; c < 4; ++c) {
      unsigned idx = c * 256 + tid;
      unsigned row = idx >> 3, ch = idx & 7;
      unsigned chs = ch ^ (row & 7);
      unsigned n = tn * 128 + row;
      const f16* src = wih16 + ((size_t)n << 10) + k0 + chs * 8;
      gl_lds16(src, (char*)Bs + c * 4096 + w * 1024);
    }
    __syncthreads();
#pragma unroll
    for (unsigned ks = 0; ks < 2; ++ks) {
      f16x8 af[4], bf[4];
      unsigned kc = ks * 4 + (lane >> 4);
#pragma unroll
      for (unsigned fm = 0; fm < 4; ++fm) {
        unsigned r = wm + fm * 16 + (lane & 15);
        af[fm] = *(const f16x8*)&As[r * 64 + ((kc ^ (r & 7)) << 3)];
      }
#pragma unroll
      for (unsigned fn = 0; fn < 4; ++fn) {
        unsigned r = wn + fn * 16 + (lane & 15);
        bf[fn] = *(const f16x8*)&Bs[r * 64 + ((kc ^ (r & 7)) << 3)];
      }
#pragma unroll
      for (unsigned fm = 0; fm < 4; ++fm)
#pragma unroll
        for (unsigned fn = 0; fn < 4; ++fn)
          acc[fm][fn] = __builtin_amdgcn_mfma_f32_16x16x32_f16(af[fm], bf[fn], acc[fm][fn], 0, 0, 0);
    }
    __syncthreads();
  }
  // epilogue: + bias, fp16 store
#pragma unroll
  for (unsigned fn = 0; fn < 4; ++fn) {
    unsigned n = tn * 128 + wn + fn * 16 + (lane & 15);
    float bv = bias[n];
#pragma unroll
    for (unsigned fm = 0; fm < 4; ++fm) {
#pragma unroll
      for (unsigned rg = 0; rg < 4; ++rg) {
        unsigned m = tm * 128 + wm + fm * 16 + (lane >> 4) * 4 + rg;
        xg[(size_t)m * G4_ + n] = (f16)(acc[fm][fn][rg] + bv);
      }
    }
  }
}

// ---------------- persistent LSTM recurrence ----------------
// 256 WGs x 128 threads. group g = bid>>7 handles batches [g*16, g*16+16);
// wid = bid&127 owns h-dims [wid*8, wid*8+8) -> 32 W_hh rows (gate-interleaved
// r = d*4+q) staged once in 64KB LDS with XOR chunk swizzle.
// Per step: A-frags (h) stream from global (fresh address per t), B-frags from
// LDS, one f32x4 accumulator (M=16,N=16 per wave), quad-shuffle gate combine.

__global__ __launch_bounds__(128) void k_lstm(
    const f16* __restrict__ xg, const f16* __restrict__ wr16,
    f16* __restrict__ h_all, unsigned* __restrict__ cnt) {
  __shared__ f16 Wl[32 * 1024];
  const unsigned tid = threadIdx.x;
  const unsigned w = tid >> 6, lane = tid & 63;
  const unsigned bid = blockIdx.x;
  const unsigned g = bid >> 7, wid = bid & 127;
  const unsigned b0 = g * 16, hbase = wid * 8;

  // stage W_hh slice (32 rows x 1024) into LDS, source-swizzled
  for (unsigned c = 0; c < 32; ++c) {
    unsigned idx = c * 128 + tid;
    unsigned r = idx >> 7, ch = idx & 127;
    unsigned chs = ch ^ (r & 7);
    const f16* src = wr16 + (((size_t)wid * 32 + r) << 10) + chs * 8;
    gl_lds16(src, (char*)Wl + c * 2048 + w * 1024);
  }
  __syncthreads();

  const unsigned r = w * 16 + (lane & 15);        // 0..31 = d*4+q
  const unsigned q = r & 3, d = r >> 2;
  const unsigned grow = q * 1024 + hbase + d;     // raw gate index in [0,4096)
  const unsigned bb0 = (lane >> 4) * 4;           // batch base for the 4 acc regs
  float c_st[4] = {0.f, 0.f, 0.f, 0.f};

  for (unsigned t = 1; t <= (unsigned)T_; ++t) {
    // x_gates prefetch (independent of h -> issues before the spin)
    float xv[4];
    {
      const f16* xp = xg + ((size_t)(t - 1) * B_ + b0 + bb0) * G4_ + grow;
#pragma unroll
      for (int z = 0; z < 4; ++z) xv[z] = (float)xp[(size_t)z * G4_];
    }
    if (t > 1) {
      if (tid == 0) {
        while (__hip_atomic_load(&cnt[g * 2049 + t - 1], __ATOMIC_ACQUIRE,
                                 __HIP_MEMORY_SCOPE_AGENT) < 128u) { }
      }
      __syncthreads();
    }
    // gates_partial = h_{t-1} @ Whh_slice^T
    f32x4 acc = {0.f, 0.f, 0.f, 0.f};
    const f16* hrow = h_all + ((size_t)(t - 1) * B_ + b0 + (lane & 15)) * H_ + (lane >> 4) * 8;
#pragma unroll
    for (unsigned ks = 0; ks < 32; ++ks) {
      f16x8 a_ = *(const f16x8*)(hrow + ks * 32);
      unsigned ck = ks * 4 + (lane >> 4);
      f16x8 b_ = *(const f16x8*)&Wl[r * 1024 + ((ck ^ (r & 7)) << 3)];
      acc = __builtin_amdgcn_mfma_f32_16x16x32_f16(a_, b_, acc, 0, 0, 0);
    }
    // activations + state update (each quad holds i,f,g,o of one (d, b-set))
    f16* hw = h_all + ((size_t)t * B_ + b0 + bb0) * H_ + hbase + d;
#pragma unroll
    for (int z = 0; z < 4; ++z) {
      float v = acc[z] + xv[z];
      float a = (q == 2) ? tanhf(v) : 1.0f / (1.0f + __expf(-v));
      float A0 = a;
      float A1 = __shfl_xor(a, 1, 64);
      float A2 = __shfl_xor(a, 2, 64);
      float A3 = __shfl_xor(a, 3, 64);
      float iact = (q == 0) ? A0 : (q == 1) ? A1 : (q == 2) ? A2 : A3;
      float fact = (q == 0) ? A1 : (q == 1) ? A0 : (q == 2) ? A3 : A2;
      float gact = (q == 0) ? A2 : (q == 1) ? A3 : (q == 2) ? A0 : A1;
      float oact = (q == 0) ? A3 : (q == 1) ? A2 : (q == 2) ? A1 : A0;
      float cn = fact * c_st[z] + iact * gact;
      c_st[z] = cn;
      float hv = oact * tanhf(cn);
      if (q == 0) hw[(size_t)z * H_] = (f16)hv;
    }
    __syncthreads();   // both waves' h stores drained (barrier implies vmcnt(0))
    if (tid == 0) {
      __threadfence(); // flush XCD L2 so other XCDs see h_all[t]
      __hip_atomic_fetch_add(&cnt[g * 2049 + t], 1u, __ATOMIC_RELEASE,
                             __HIP_MEMORY_SCOPE_AGENT);
    }
  }
}

// ---------------- logits: out[b][t][c] = relu(h[t+1]) . W_score[c] ----------------

__global__ __launch_bounds__(256) void k_logits(
    const f16* __restrict__ h_all, const float* __restrict__ wsc,
    float* __restrict__ out) {
  __shared__ float Ws[2048];
  unsigned tid = threadIdx.x;
  for (unsigned i = tid; i < 512; i += 256) ((float4*)Ws)[i] = ((const float4*)wsc)[i];
  __syncthreads();
  unsigned w = tid >> 6, lane = tid & 63;
  unsigned base = blockIdx.x * 64 + w * 16;
  for (unsigned i = 0; i < 16; ++i) {
    unsigned idx = base + i;                // 0..65535
    unsigned tt = idx >> 5, b = idx & 31;
    const f16* hp = h_all + ((size_t)(idx + 32)) * H_ + lane * 16;
    f16x8 ha = *(const f16x8*)hp;
    f16x8 hb = *(const f16x8*)(hp + 8);
    float s0 = 0.f, s1 = 0.f;
#pragma unroll
    for (int z = 0; z < 8; ++z) {
      float hv = fmaxf((float)ha[z], 0.f);
      s0 += hv * Ws[lane * 16 + z];
      s1 += hv * Ws[1024 + lane * 16 + z];
    }
#pragma unroll
    for (int z = 0; z < 8; ++z) {
      float hv = fmaxf((float)hb[z], 0.f);
      s0 += hv * Ws[lane * 16 + 8 + z];
      s1 += hv * Ws[1024 + lane * 16 + 8 + z];
    }
#pragma unroll
    for (int off = 32; off; off >>= 1) {
      s0 += __shfl_xor(s0, off, 64);
      s1 += __shfl_xor(s1, off, 64);
    }
    if (lane == 0) {
      out[((size_t)b * T_ + tt) * 2 + 0] = s0;
      out[((size_t)b * T_ + tt) * 2 + 1] = s1;
    }
  }
}

// ---------------- launch ----------------

extern "C" void kernel_launch(void* const* d_in, const int* in_sizes, int n_in,
                              void* d_out, int out_size, void* d_ws, size_t ws_size,
                              hipStream_t stream) {
  const int*   seq = (const int*)d_in[0];
  const float* emb = (const float*)d_in[1];
  const float* wih = (const float*)d_in[2];
  const float* whh = (const float*)d_in[3];
  const float* bih = (const float*)d_in[4];
  const float* bhh = (const float*)d_in[5];
  const float* wsc = (const float*)d_in[6];
  float* out = (float*)d_out;
  char* ws = (char*)d_ws;

  const size_t NEED = 790890504ull;
  if (ws_size < NEED) return;  // workspace too small: output stays zero (detectable)

  f16*      emb16 = (f16*)(ws);
  f16*      wih16 = (f16*)(ws + 102926336ull);
  f16*      wr16  = (f16*)(ws + 111314944ull);
  float*    bias  = (float*)(ws + 119703552ull);
  f16*      xg    = (f16*)(ws + 119719936ull);
  f16*      h_all = (f16*)(ws + 656590848ull);
  unsigned* cnt   = (unsigned*)(ws + 790874112ull);

  hipMemsetAsync(h_all, 0, (size_t)B_ * H_ * 2, stream);      // h_0 = 0
  hipMemsetAsync(cnt, 0, 2 * 2049 * 4, stream);               // step flags

  k_cvt_f16<<<50257, 256, 0, stream>>>(emb, emb16, 12865792L);
  k_cvt_f16<<<4096, 256, 0, stream>>>(wih, wih16, 1048576L);
  k_whh_reorder<<<2048, 256, 0, stream>>>(whh, wr16);
  k_bias<<<16, 256, 0, stream>>>(bih, bhh, bias);

  k_gemm_xg<<<16384, 256, 0, stream>>>(seq, emb16, wih16, bias, xg);
  k_lstm<<<256, 128, 0, stream>>>(xg, wr16, h_all, cnt);
  k_logits<<<1024, 256, 0, stream>>>(h_all, wsc, out);
}

// Round 2
// 25582.417 us; speedup vs baseline: 1.7097x; 1.7097x over previous
//
#include <hip/hip_runtime.h>
#include <hip/hip_bf16.h>

// LSTM classifier: emb gather -> input GEMM (fp16 MFMA) -> persistent
// recurrence kernel (64 WGs x 512 thr, flag-store sync) -> logits.
//
// Workspace layout (bytes):
//   emb16   @ 0          : 50257*1024*2 = 102,926,336
//   wih16   @ 102926336  : 4096*1024*2  =   8,388,608
//   wr16    @ 111314944  : 4096*1024*2  =   8,388,608   (W_hh reordered, fp16)
//   bias    @ 119703552  : 4096*4       =      16,384   (b_ih + b_hh, f32)
//   xg      @ 119719936  : 65536*4096*2 = 536,870,912   (x_gates fp16, [t][b][R'])
//   h_all   @ 656590848  : 2049*32*1024*2 = 134,283,264 (h per step, fp16)
//   flags   @ 790874112  : 64*32*4      =       8,192   (per-WG step flags)
//   total: 790,882,304

typedef _Float16 f16;
typedef _Float16 f16x8 __attribute__((ext_vector_type(8)));
typedef _Float16 f16x4 __attribute__((ext_vector_type(4)));
typedef float    f32x4 __attribute__((ext_vector_type(4)));

#define B_    32
#define T_    2048
#define W_    1024
#define H_    1024
#define G4_   4096

__device__ __forceinline__ void gl_lds16(const void* g, void* l) {
  __builtin_amdgcn_global_load_lds(
      (const __attribute__((address_space(1))) void*)g,
      (__attribute__((address_space(3))) void*)l, 16, 0, 0);
}

// ---------------- conversions ----------------

__global__ void k_cvt_f16(const float* __restrict__ in, f16* __restrict__ out, long n4) {
  long i = (long)blockIdx.x * blockDim.x + threadIdx.x;
  if (i >= n4) return;
  float4 v = ((const float4*)in)[i];
  f16x4 o; o[0] = (f16)v.x; o[1] = (f16)v.y; o[2] = (f16)v.z; o[3] = (f16)v.w;
  *(f16x4*)(out + i * 4) = o;
}

// W_hh row (q*1024 + j) -> wr16 row R' = (j>>4)*64 + (j&15)*4 + q; fp16.
// => WG wid owns contiguous rows [wid*64, wid*64+64) = h-dims [wid*16, +16).
__global__ void k_whh_reorder(const float* __restrict__ whh, f16* __restrict__ wr) {
  unsigned i = blockIdx.x * blockDim.x + threadIdx.x;   // one thread per 8 elems
  unsigned e0 = i * 8;
  unsigned R = e0 >> 10, k = e0 & 1023;
  unsigned q = R >> 10, j = R & 1023;
  unsigned outR = ((j >> 4) << 6) + ((j & 15) << 2) + q;
  float4 v0 = ((const float4*)whh)[e0 / 4];
  float4 v1 = ((const float4*)whh)[e0 / 4 + 1];
  f16x8 o;
  o[0] = (f16)v0.x; o[1] = (f16)v0.y; o[2] = (f16)v0.z; o[3] = (f16)v0.w;
  o[4] = (f16)v1.x; o[5] = (f16)v1.y; o[6] = (f16)v1.z; o[7] = (f16)v1.w;
  *(f16x8*)&wr[((size_t)outR << 10) + k] = o;
}

__global__ void k_bias(const float* __restrict__ bi, const float* __restrict__ bh,
                       float* __restrict__ bo) {
  unsigned i = blockIdx.x * blockDim.x + threadIdx.x;
  if (i < G4_) bo[i] = bi[i] + bh[i];
}

// ---------------- input GEMM: xg[m][R'(n)] = emb[seq] @ W_ih^T + bias ----------------
// m = t*32 + b (so xg layout is [t][b][R']); 128x128 tile, BK=64, 4 waves.

__global__ __launch_bounds__(256) void k_gemm_xg(
    const int* __restrict__ seq, const f16* __restrict__ emb16,
    const f16* __restrict__ wih16, const float* __restrict__ bias,
    f16* __restrict__ xg) {
  __shared__ f16 As[128 * 64];
  __shared__ f16 Bs[128 * 64];
  const unsigned tid = threadIdx.x;
  const unsigned w = tid >> 6, lane = tid & 63;
  const unsigned bid = blockIdx.x;
  const unsigned tn = bid & 31, tm = bid >> 5;
  const unsigned wm = (w >> 1) * 64, wn = (w & 1) * 64;

  f32x4 zero = {0.f, 0.f, 0.f, 0.f};
  f32x4 acc[4][4];
#pragma unroll
  for (int i = 0; i < 4; ++i)
#pragma unroll
    for (int j = 0; j < 4; ++j) acc[i][j] = zero;

  for (unsigned kk = 0; kk < 16; ++kk) {
    const unsigned k0 = kk * 64;
#pragma unroll
    for (unsigned c = 0; c < 4; ++c) {
      unsigned idx = c * 256 + tid;
      unsigned row = idx >> 3, ch = idx & 7;
      unsigned chs = ch ^ (row & 7);
      unsigned m = tm * 128 + row;
      unsigned t = m >> 5, b = m & 31;
      int e = seq[b * 2048 + t];
      const f16* src = emb16 + ((size_t)e << 10) + k0 + chs * 8;
      gl_lds16(src, (char*)As + c * 4096 + w * 1024);
    }
#pragma unroll
    for (unsigned c = 0; c < 4; ++c) {
      unsigned idx = c * 256 + tid;
      unsigned row = idx >> 3, ch = idx & 7;
      unsigned chs = ch ^ (row & 7);
      unsigned n = tn * 128 + row;
      const f16* src = wih16 + ((size_t)n << 10) + k0 + chs * 8;
      gl_lds16(src, (char*)Bs + c * 4096 + w * 1024);
    }
    __syncthreads();
#pragma unroll
    for (unsigned ks = 0; ks < 2; ++ks) {
      f16x8 af[4], bf[4];
      unsigned kc = ks * 4 + (lane >> 4);
#pragma unroll
      for (unsigned fm = 0; fm < 4; ++fm) {
        unsigned r = wm + fm * 16 + (lane & 15);
        af[fm] = *(const f16x8*)&As[r * 64 + ((kc ^ (r & 7)) << 3)];
      }
#pragma unroll
      for (unsigned fn = 0; fn < 4; ++fn) {
        unsigned r = wn + fn * 16 + (lane & 15);
        bf[fn] = *(const f16x8*)&Bs[r * 64 + ((kc ^ (r & 7)) << 3)];
      }
#pragma unroll
      for (unsigned fm = 0; fm < 4; ++fm)
#pragma unroll
        for (unsigned fn = 0; fn < 4; ++fn)
          acc[fm][fn] = __builtin_amdgcn_mfma_f32_16x16x32_f16(af[fm], bf[fn], acc[fm][fn], 0, 0, 0);
    }
    __syncthreads();
  }
  // epilogue: + bias, fp16 store into gate-interleaved layout R'
#pragma unroll
  for (unsigned fn = 0; fn < 4; ++fn) {
    unsigned n = tn * 128 + wn + fn * 16 + (lane & 15);
    unsigned q = n >> 10, j = n & 1023;
    unsigned Rp = ((j >> 4) << 6) + ((j & 15) << 2) + q;
    float bv = bias[n];
#pragma unroll
    for (unsigned fm = 0; fm < 4; ++fm) {
#pragma unroll
      for (unsigned rg = 0; rg < 4; ++rg) {
        unsigned m = tm * 128 + wm + fm * 16 + (lane >> 4) * 4 + rg;
        xg[(size_t)m * G4_ + Rp] = (f16)(acc[fm][fn][rg] + bv);
      }
    }
  }
}

// ---------------- persistent LSTM recurrence ----------------
// 64 WGs x 512 threads (8 waves = 2 M-tiles x 4 N-tiles). WG wid owns h-dims
// [wid*16, wid*16+16) -> 64 gate-interleaved rows staged once in 128KB LDS.
// Per step: A-frags (h) from global (L2/LLC), B-frags from LDS, one f32x4
// accumulator per wave (M=16,N=16,K=1024), quad-shuffle gate combine.
// Sync: writer stores flag[wid]=t (release, own 128B line, NO RMW);
// readers: wave0's 64 lanes poll the 64 flags, __all(v>=t-1) exit.

__global__ __launch_bounds__(512) void k_lstm(
    const f16* __restrict__ xg, const f16* __restrict__ wr16,
    f16* __restrict__ h_all, unsigned* __restrict__ flags) {
  __shared__ f16 Wl[64 * 1024];     // 128 KB
  const unsigned tid = threadIdx.x;
  const unsigned w = tid >> 6, lane = tid & 63;
  const unsigned wid = blockIdx.x;          // 0..63
  const unsigned mt = w >> 2, nt = w & 3;

  // stage W_hh slice (64 rows x 1024 f16), source-swizzled, linear LDS dest
  for (unsigned c = 0; c < 16; ++c) {
    unsigned idx = c * 512 + tid;
    unsigned row = idx >> 7, ch = idx & 127;
    unsigned chs = ch ^ (row & 7);
    const f16* src = wr16 + (((size_t)wid * 64 + row) << 10) + chs * 8;
    gl_lds16(src, (char*)Wl + c * 8192 + w * 1024);
  }
  __syncthreads();

  const unsigned rl = lane & 15, hi = lane >> 4;
  const unsigned q = rl & 3;                 // gate id within quad
  const unsigned rWl = nt * 16 + rl;         // local W row 0..63
  const unsigned bB = mt * 16 + hi * 4;      // batch base for the 4 acc regs
  const unsigned d = wid * 16 + nt * 4 + (rl >> 2);
  float c_st[4] = {0.f, 0.f, 0.f, 0.f};

  for (unsigned t = 1; t <= (unsigned)T_; ++t) {
    // x_gates prefetch (independent of h -> issues before the poll)
    float xv[4];
    {
      const f16* xp = xg + ((size_t)(t - 1) * B_ + bB) * G4_ + wid * 64 + rWl;
#pragma unroll
      for (int z = 0; z < 4; ++z) xv[z] = (float)xp[(size_t)z * G4_];
    }
    if (t > 1) {
      if (tid < 64) {
        while (true) {
          unsigned v = __hip_atomic_load(&flags[tid * 32], __ATOMIC_ACQUIRE,
                                         __HIP_MEMORY_SCOPE_AGENT);
          if (__all((int)(v >= t - 1))) break;
        }
      }
      __syncthreads();
    }
    // gates_partial = h_{t-1}[m-tile] @ Whh_slice[n-tile]^T
    f32x4 acc = {0.f, 0.f, 0.f, 0.f};
    const f16* hrow = h_all + ((size_t)(t - 1) * B_ + mt * 16 + rl) * H_ + hi * 8;
#pragma unroll
    for (unsigned ks = 0; ks < 32; ++ks) {
      f16x8 a_ = *(const f16x8*)(hrow + ks * 32);
      unsigned ck = ks * 4 + hi;
      f16x8 b_ = *(const f16x8*)&Wl[rWl * 1024 + ((ck ^ (rWl & 7)) << 3)];
      acc = __builtin_amdgcn_mfma_f32_16x16x32_f16(a_, b_, acc, 0, 0, 0);
    }
    // activations + state update (each quad holds i,f,g,o of one (d, b-set))
    f16* hw = h_all + ((size_t)t * B_ + bB) * H_ + d;
#pragma unroll
    for (int z = 0; z < 4; ++z) {
      float v = acc[z] + xv[z];
      float a = (q == 2) ? tanhf(v) : 1.0f / (1.0f + __expf(-v));
      float A1 = __shfl_xor(a, 1, 64);
      float A2 = __shfl_xor(a, 2, 64);
      float A3 = __shfl_xor(a, 3, 64);
      float iact = (q == 0) ? a  : (q == 1) ? A1 : (q == 2) ? A2 : A3;
      float fact = (q == 0) ? A1 : (q == 1) ? a  : (q == 2) ? A3 : A2;
      float gact = (q == 0) ? A2 : (q == 1) ? A3 : (q == 2) ? a  : A1;
      float oact = (q == 0) ? A3 : (q == 1) ? A2 : (q == 2) ? A1 : a;
      float cn = fact * c_st[z] + iact * gact;
      c_st[z] = cn;
      float hv = oact * tanhf(cn);
      if (q == 0) hw[(size_t)z * H_] = (f16)hv;
    }
    __syncthreads();   // all waves' h stores drained (vmcnt(0) before barrier)
    if (tid == 0) {
      __threadfence(); // flush XCD L2 so other XCDs see h_all[t]
      __hip_atomic_store(&flags[wid * 32], t, __ATOMIC_RELEASE,
                         __HIP_MEMORY_SCOPE_AGENT);
    }
  }
}

// ---------------- logits: out[b][t][c] = relu(h[t+1]) . W_score[c] ----------------

__global__ __launch_bounds__(256) void k_logits(
    const f16* __restrict__ h_all, const float* __restrict__ wsc,
    float* __restrict__ out) {
  __shared__ float Ws[2048];
  unsigned tid = threadIdx.x;
  for (unsigned i = tid; i < 512; i += 256) ((float4*)Ws)[i] = ((const float4*)wsc)[i];
  __syncthreads();
  unsigned w = tid >> 6, lane = tid & 63;
  unsigned base = blockIdx.x * 64 + w * 16;
  for (unsigned i = 0; i < 16; ++i) {
    unsigned idx = base + i;                // 0..65535
    unsigned tt = idx >> 5, b = idx & 31;
    const f16* hp = h_all + ((size_t)(idx + 32)) * H_ + lane * 16;
    f16x8 ha = *(const f16x8*)hp;
    f16x8 hb = *(const f16x8*)(hp + 8);
    float s0 = 0.f, s1 = 0.f;
#pragma unroll
    for (int z = 0; z < 8; ++z) {
      float hv = fmaxf((float)ha[z], 0.f);
      s0 += hv * Ws[lane * 16 + z];
      s1 += hv * Ws[1024 + lane * 16 + z];
    }
#pragma unroll
    for (int z = 0; z < 8; ++z) {
      float hv = fmaxf((float)hb[z], 0.f);
      s0 += hv * Ws[lane * 16 + 8 + z];
      s1 += hv * Ws[1024 + lane * 16 + 8 + z];
    }
#pragma unroll
    for (int off = 32; off; off >>= 1) {
      s0 += __shfl_xor(s0, off, 64);
      s1 += __shfl_xor(s1, off, 64);
    }
    if (lane == 0) {
      out[((size_t)b * T_ + tt) * 2 + 0] = s0;
      out[((size_t)b * T_ + tt) * 2 + 1] = s1;
    }
  }
}

// ---------------- launch ----------------

extern "C" void kernel_launch(void* const* d_in, const int* in_sizes, int n_in,
                              void* d_out, int out_size, void* d_ws, size_t ws_size,
                              hipStream_t stream) {
  const int*   seq = (const int*)d_in[0];
  const float* emb = (const float*)d_in[1];
  const float* wih = (const float*)d_in[2];
  const float* whh = (const float*)d_in[3];
  const float* bih = (const float*)d_in[4];
  const float* bhh = (const float*)d_in[5];
  const float* wsc = (const float*)d_in[6];
  float* out = (float*)d_out;
  char* ws = (char*)d_ws;

  const size_t NEED = 790882304ull;
  if (ws_size < NEED) return;  // workspace too small: output stays zero (detectable)

  f16*      emb16 = (f16*)(ws);
  f16*      wih16 = (f16*)(ws + 102926336ull);
  f16*      wr16  = (f16*)(ws + 111314944ull);
  float*    bias  = (float*)(ws + 119703552ull);
  f16*      xg    = (f16*)(ws + 119719936ull);
  f16*      h_all = (f16*)(ws + 656590848ull);
  unsigned* flags = (unsigned*)(ws + 790874112ull);

  hipMemsetAsync(h_all, 0, (size_t)B_ * H_ * 2, stream);      // h_0 = 0
  hipMemsetAsync(flags, 0, 64 * 32 * 4, stream);              // step flags

  k_cvt_f16<<<50257, 256, 0, stream>>>(emb, emb16, 12865792L);
  k_cvt_f16<<<4096, 256, 0, stream>>>(wih, wih16, 1048576L);
  k_whh_reorder<<<2048, 256, 0, stream>>>(whh, wr16);
  k_bias<<<16, 256, 0, stream>>>(bih, bhh, bias);

  k_gemm_xg<<<16384, 256, 0, stream>>>(seq, emb16, wih16, bias, xg);
  k_lstm<<<64, 512, 0, stream>>>(xg, wr16, h_all, flags);
  k_logits<<<1024, 256, 0, stream>>>(h_all, wsc, out);
}